// Round 13
// baseline (158.803 us; speedup 1.0000x reference)
//
#include <hip/hip_runtime.h>
#include <hip/hip_bf16.h>
#include <hip/hip_fp16.h>

#define F 128
#define HID 64
#define KMAX 4
#define DEG_CAP 256   // KMAX * 64
#define NTM 16        // nodes per block in fused_front MLP
#define NTU 16        // nodes per block in agg_update
#define CHUNK_LOG 14
#define CHUNK (1 << CHUNK_LOG)   // 16384 edges per histogram block

// All sort-index arrays are u16: src ids < 10000, per-chunk rank < 16384,
// per-chunk counts <= 16384, within-bin chunk offsets <= max degree (~120).
// fill also scatters ps_sorted[pos] = p[src[i]] (fp32) so agg's softmax
// reads scores COALESCED instead of doing 640K random p-gathers at low
// occupancy (fill's 2500 blocks hide the gather latency instead).

// ---------------------------------------------------------------------------
// fused_front: blocks [0, histBlocks) build per-chunk LDS histograms (n=10000
// counters = 40KB LDS, ds_add_rtn) + per-edge local rank (u16), then dump the
// count row packed u16 to cnt[blk*n..]. No global atomics at all.
// Blocks [histBlocks, ...): node message MLP in the v5 K-split-by-wave form.
// ---------------------------------------------------------------------------
__global__ __launch_bounds__(256) void fused_front(
    const int* __restrict__ dst, unsigned short* __restrict__ cnt,
    unsigned short* __restrict__ rank,
    int e, int n, int histBlocks,
    const float* __restrict__ h,
    const float* __restrict__ W1, const float* __restrict__ b1,
    const float* __restrict__ W2, const float* __restrict__ b2,
    const float* __restrict__ nk, const float* __restrict__ attn,
    __half* __restrict__ Mh, float* __restrict__ p, float* __restrict__ q)
{
    __shared__ __align__(16) int lhist[10240];   // 40960B union
    int tid = threadIdx.x;

    if ((int)blockIdx.x < histBlocks) {
        // ---------------- LDS histogram part ----------------
        int n4 = n >> 2;
        int4* lh4 = (int4*)lhist;
        for (int i = tid; i < n4; i += 256) lh4[i] = make_int4(0, 0, 0, 0);
        for (int i = (n4 << 2) + tid; i < n; i += 256) lhist[i] = 0;
        __syncthreads();

        int base = (int)blockIdx.x << CHUNK_LOG;
        int lim = min(e - base, CHUNK);
        int lim4 = lim >> 2;
        const int4* d4 = (const int4*)(dst + base);   // base is 64KB-aligned
        for (int k = tid; k < lim4; k += 256) {
            int4 dv = d4[k];
            ushort4 rv;
            rv.x = (unsigned short)atomicAdd(&lhist[dv.x], 1);
            rv.y = (unsigned short)atomicAdd(&lhist[dv.y], 1);
            rv.z = (unsigned short)atomicAdd(&lhist[dv.z], 1);
            rv.w = (unsigned short)atomicAdd(&lhist[dv.w], 1);
            *(ushort4*)&rank[base + 4 * k] = rv;       // 8B aligned
        }
        for (int k = (lim4 << 2) + tid; k < lim; k += 256)
            rank[base + k] = (unsigned short)atomicAdd(&lhist[dst[base + k]], 1);
        __syncthreads();

        // dump counts packed 2-per-u32 (n is even)
        unsigned int* crow = (unsigned int*)(cnt + (size_t)blockIdx.x * n);
        int nh = n >> 1;
        for (int i = tid; i < nh; i += 256) {
            unsigned int v = ((unsigned int)lhist[2 * i] & 0xffffu) |
                             ((unsigned int)lhist[2 * i + 1] << 16);
            crow[i] = v;
        }
        return;
    }

    // ---------------- node MLP part (K-split by wave) ----------------
    float* smem = (float*)lhist;   // 10240 floats
    int bm = blockIdx.x - histBlocks;
    int row0 = bm * NTM;
    int wv   = tid >> 6;
    int lane = tid & 63;
    int j0 = (lane & 31) * 4;     // output col quad
    int rh = (lane >> 5) * 8;     // row-half: rows rh..rh+7

    // stage X = h[16][128] at [0,2048)
    #pragma unroll
    for (int it = 0; it < 2; ++it) {
        int s4 = tid + it * 256;
        int r = s4 >> 5, c4 = s4 & 31;
        int row = row0 + r;
        float4 v = make_float4(0, 0, 0, 0);
        if (row < n) v = *(const float4*)&h[(size_t)row * F + c4 * 4];
        *(float4*)&smem[r * F + c4 * 4] = v;
    }
    __syncthreads();

    // q = h . attn[F:]  (16 threads/row, 8 elems each)
    {
        int r = tid >> 4, kp = tid & 15;
        float qa = 0.f;
        #pragma unroll
        for (int c = 0; c < 2; ++c) {
            float4 hv = *(const float4*)&smem[r * F + kp * 8 + c * 4];
            float4 av = *(const float4*)&attn[F + kp * 8 + c * 4];
            qa = fmaf(hv.x, av.x, qa); qa = fmaf(hv.y, av.y, qa);
            qa = fmaf(hv.z, av.z, qa); qa = fmaf(hv.w, av.w, qa);
        }
        #pragma unroll
        for (int off = 1; off < 16; off <<= 1) qa += __shfl_xor(qa, off, 64);
        int row = row0 + r;
        if (kp == 0 && row < n) q[row] = qa;
    }

    // ---- layer 1: T = relu(h @ W1 + b1), K=128, wave k-slice 32 ----
    float4 acc[8];
    #pragma unroll
    for (int i = 0; i < 8; ++i) acc[i] = make_float4(0.f, 0.f, 0.f, 0.f);
    int kbase = wv * 32;
    for (int k4 = 0; k4 < 8; ++k4) {
        int kk = kbase + k4 * 4;
        float4 a[8];
        #pragma unroll
        for (int r = 0; r < 8; ++r) a[r] = *(const float4*)&smem[(rh + r) * F + kk];
        #pragma unroll
        for (int k = 0; k < 4; ++k) {
            float4 b = *(const float4*)&W1[(size_t)(kk + k) * F + j0];
            #pragma unroll
            for (int r = 0; r < 8; ++r) {
                float av = k == 0 ? a[r].x : k == 1 ? a[r].y : k == 2 ? a[r].z : a[r].w;
                acc[r].x = fmaf(av, b.x, acc[r].x);
                acc[r].y = fmaf(av, b.y, acc[r].y);
                acc[r].z = fmaf(av, b.z, acc[r].z);
                acc[r].w = fmaf(av, b.w, acc[r].w);
            }
        }
    }
    __syncthreads();   // all X reads (incl. q) done

    // red[wv][row][col] at [2048 + wv*2048)
    #pragma unroll
    for (int r = 0; r < 8; ++r)
        *(float4*)&smem[2048 + wv * 2048 + (rh + r) * 128 + j0] = acc[r];
    __syncthreads();

    // reduce + b1 + relu -> T at [0,2048)  (aliases X, dead)
    #pragma unroll
    for (int u = 0; u < 2; ++u) {
        int idx = tid * 2 + u;
        int row = idx >> 5, c4 = (idx & 31) * 4;
        float4 s0 = *(const float4*)&smem[2048 + 0 * 2048 + row * 128 + c4];
        float4 s1 = *(const float4*)&smem[2048 + 1 * 2048 + row * 128 + c4];
        float4 s2 = *(const float4*)&smem[2048 + 2 * 2048 + row * 128 + c4];
        float4 s3 = *(const float4*)&smem[2048 + 3 * 2048 + row * 128 + c4];
        float4 bv = *(const float4*)&b1[c4];
        float4 t;
        t.x = fmaxf(s0.x + s1.x + s2.x + s3.x + bv.x, 0.f);
        t.y = fmaxf(s0.y + s1.y + s2.y + s3.y + bv.y, 0.f);
        t.z = fmaxf(s0.z + s1.z + s2.z + s3.z + bv.z, 0.f);
        t.w = fmaxf(s0.w + s1.w + s2.w + s3.w + bv.w, 0.f);
        *(float4*)&smem[row * 128 + c4] = t;
    }
    __syncthreads();

    // ---- layer 2: M = T @ W2 + b2, K=128, wave k-slice 32 ----
    #pragma unroll
    for (int i = 0; i < 8; ++i) acc[i] = make_float4(0.f, 0.f, 0.f, 0.f);
    for (int k4 = 0; k4 < 8; ++k4) {
        int kk = kbase + k4 * 4;
        float4 a[8];
        #pragma unroll
        for (int r = 0; r < 8; ++r) a[r] = *(const float4*)&smem[(rh + r) * 128 + kk];
        #pragma unroll
        for (int k = 0; k < 4; ++k) {
            float4 b = *(const float4*)&W2[(size_t)(kk + k) * F + j0];
            #pragma unroll
            for (int r = 0; r < 8; ++r) {
                float av = k == 0 ? a[r].x : k == 1 ? a[r].y : k == 2 ? a[r].z : a[r].w;
                acc[r].x = fmaf(av, b.x, acc[r].x);
                acc[r].y = fmaf(av, b.y, acc[r].y);
                acc[r].z = fmaf(av, b.z, acc[r].z);
                acc[r].w = fmaf(av, b.w, acc[r].w);
            }
        }
    }
    __syncthreads();   // all T reads done
    #pragma unroll
    for (int r = 0; r < 8; ++r)
        *(float4*)&smem[2048 + wv * 2048 + (rh + r) * 128 + j0] = acc[r];
    __syncthreads();

    // reduce + b2 -> M at [0,2048)  (aliases T, dead)
    #pragma unroll
    for (int u = 0; u < 2; ++u) {
        int idx = tid * 2 + u;
        int row = idx >> 5, c4 = (idx & 31) * 4;
        float4 s0 = *(const float4*)&smem[2048 + 0 * 2048 + row * 128 + c4];
        float4 s1 = *(const float4*)&smem[2048 + 1 * 2048 + row * 128 + c4];
        float4 s2 = *(const float4*)&smem[2048 + 2 * 2048 + row * 128 + c4];
        float4 s3 = *(const float4*)&smem[2048 + 3 * 2048 + row * 128 + c4];
        float4 bv = *(const float4*)&b2[c4];
        float4 t;
        t.x = s0.x + s1.x + s2.x + s3.x + bv.x;
        t.y = s0.y + s1.y + s2.y + s3.y + bv.y;
        t.z = s0.z + s1.z + s2.z + s3.z + bv.z;
        t.w = s0.w + s1.w + s2.w + s3.w + bv.w;
        *(float4*)&smem[row * 128 + c4] = t;
    }
    __syncthreads();

    // v1 = node_kernel @ attn[:F] -> [2048,2176)  (red region, dead)
    if (tid < F) {
        float a = 0.f;
        const float4* nkr = (const float4*)&nk[(size_t)tid * F];
        const float4* at4 = (const float4*)attn;
        #pragma unroll 8
        for (int j = 0; j < 32; ++j) {
            float4 nv = nkr[j]; float4 av = at4[j];
            a = fmaf(nv.x, av.x, a); a = fmaf(nv.y, av.y, a);
            a = fmaf(nv.z, av.z, a); a = fmaf(nv.w, av.w, a);
        }
        smem[2048 + tid] = a;
    }
    __syncthreads();

    // Mh (fp16) store + p = M.v1   (thread = row, 8-col segment)
    {
        int row = tid >> 4, c8 = (tid & 15) * 8;
        int grow = row0 + row;
        float4 m0 = *(const float4*)&smem[row * 128 + c8];
        float4 m1 = *(const float4*)&smem[row * 128 + c8 + 4];
        if (grow < n) {
            __half hv[8];
            hv[0] = __float2half(m0.x); hv[1] = __float2half(m0.y);
            hv[2] = __float2half(m0.z); hv[3] = __float2half(m0.w);
            hv[4] = __float2half(m1.x); hv[5] = __float2half(m1.y);
            hv[6] = __float2half(m1.z); hv[7] = __float2half(m1.w);
            *(uint4*)&Mh[(size_t)grow * F + c8] = *(uint4*)hv;
        }
        float4 v0 = *(const float4*)&smem[2048 + c8];
        float4 v1v = *(const float4*)&smem[2048 + c8 + 4];
        float pp = m0.x * v0.x + m0.y * v0.y + m0.z * v0.z + m0.w * v0.w +
                   m1.x * v1v.x + m1.y * v1v.y + m1.z * v1v.z + m1.w * v1v.w;
        #pragma unroll
        for (int off = 1; off < 16; off <<= 1) pp += __shfl_xor(pp, off, 64);
        if ((tid & 15) == 0 && grow < n) p[grow] = pp;
    }
}

// ---------------------------------------------------------------------------
// scan_block v2: 1024 threads/block, 4 thread-groups per node each owning
// ~hb/4 chunk rows: pass-1 partial sums, LDS combine, pass-2 rewrite.
// ---------------------------------------------------------------------------
__global__ __launch_bounds__(1024) void scan_block(
    unsigned short* __restrict__ cnt, int* __restrict__ rstart,
    int* __restrict__ bsum, int n, int hb)
{
    __shared__ int psum[4][256];
    __shared__ int wsum[4];
    int tid = threadIdx.x;
    int ln = tid & 255, g = tid >> 8;          // group 0..3
    int i = blockIdx.x * 256 + ln;
    int per = (hb + 3) >> 2;
    int r0 = g * per, r1 = min(hb, r0 + per);

    // pass 1: partial sum over this group's chunk rows
    int s = 0;
    if (i < n) {
        size_t idx = (size_t)r0 * n + i;
        int r = r0;
        for (; r + 4 <= r1; r += 4) {
            int c0 = cnt[idx];
            int c1 = cnt[idx + (size_t)n];
            int c2 = cnt[idx + 2 * (size_t)n];
            int c3 = cnt[idx + 3 * (size_t)n];
            s += c0 + c1 + c2 + c3;
            idx += 4 * (size_t)n;
        }
        for (; r < r1; ++r) { s += cnt[idx]; idx += n; }
    }
    psum[g][ln] = s;
    __syncthreads();

    int base = 0;
    #pragma unroll
    for (int gg = 0; gg < 3; ++gg) base += (gg < g) ? psum[gg][ln] : 0;
    int tot = psum[0][ln] + psum[1][ln] + psum[2][ln] + psum[3][ln];

    // pass 2: rewrite this group's rows with running offsets
    if (i < n) {
        size_t idx = (size_t)r0 * n + i;
        int run = base;
        for (int r = r0; r < r1; ++r) {
            int c = cnt[idx];
            cnt[idx] = (unsigned short)run;
            run += c;
            idx += n;
        }
    }

    // rstart/bsum: group 0 scans node totals
    int lane = ln & 63, wv4 = ln >> 6;
    int x = 0, v = 0;
    if (g == 0) {
        v = (i < n) ? tot : 0;
        x = v;
        #pragma unroll
        for (int off = 1; off < 64; off <<= 1) {
            int t = __shfl_up(x, off, 64);
            if (lane >= off) x += t;
        }
        if (lane == 63) wsum[wv4] = x;
    }
    __syncthreads();
    if (g == 0) {
        int woff = 0;
        #pragma unroll
        for (int wdx = 0; wdx < 4; ++wdx) woff += (wdx < wv4) ? wsum[wdx] : 0;
        int incl = x + woff;
        if (i < n) rstart[i] = incl - v;
        if (ln == 255) bsum[blockIdx.x] = incl;
    }
}

// ---------------------------------------------------------------------------
// fill: atomic-free scatter; also scatters ps_sorted[pos] = p[src[i]] so the
// agg softmax reads scores coalesced (p gather hidden here by 2500-block TLP).
// ---------------------------------------------------------------------------
__global__ __launch_bounds__(256) void fill_kernel(
    const int* __restrict__ dst, const int* __restrict__ src,
    const unsigned short* __restrict__ rank, const int* __restrict__ rstart,
    const unsigned short* __restrict__ cntoff, const int* __restrict__ bsum,
    const float* __restrict__ p,
    unsigned short* __restrict__ src_sorted, float* __restrict__ ps_sorted,
    int n, int nb, int e)
{
    __shared__ int sbo[64];
    int tid = threadIdx.x;
    if (tid < 64) {
        int v = (tid < nb) ? bsum[tid] : 0;
        int x = v;
        #pragma unroll
        for (int off = 1; off < 64; off <<= 1) {
            int t = __shfl_up(x, off, 64);
            if (tid >= off) x += t;
        }
        sbo[tid] = x - v;
    }
    __syncthreads();
    int i = blockIdx.x * 256 + tid;
    if (i < e) {
        int d = dst[i];
        int sv = src[i];
        int rep = i >> CHUNK_LOG;
        int pos = rstart[d] + sbo[d >> 8] + (int)cntoff[(size_t)rep * n + d] + (int)rank[i];
        src_sorted[pos] = (unsigned short)sv;
        ps_sorted[pos]  = p[sv];
    }
}

// ---------------------------------------------------------------------------
// agg_update: FUSED segment-softmax gather + update/readout MLP.
// Softmax scores read coalesced from ps_sorted (no random p gathers).
// ---------------------------------------------------------------------------
__global__ __launch_bounds__(256) void agg_update(
    const __half* __restrict__ Mh, const float* __restrict__ ps_sorted,
    const float* __restrict__ q, const int* __restrict__ rstart,
    const int* __restrict__ bsum, const unsigned short* __restrict__ src_sorted,
    const float* __restrict__ h,
    const float* __restrict__ Wu, const float* __restrict__ bu,
    const float* __restrict__ Wr1, const float* __restrict__ br1,
    const float* __restrict__ Wr2, const float* __restrict__ br2,
    float* __restrict__ out, int n, int nb, int e)
{
    __shared__ __align__(16) float smem[8192];       // 32KB union
    float (*X)[2 * F] = (float (*)[2 * F])smem;      // [16][256] = 16KB
    int2* bufa = (int2*)&smem[4096];                 // [4][DEG_CAP] = 8KB
    int*  sbo  = (int*)&smem[6144];                  // 64 ints

    int tid = threadIdx.x;
    int wv   = tid >> 6;
    int lane = tid & 63;
    int row0 = blockIdx.x * NTU;

    if (tid < 64) {
        int v = (tid < nb) ? bsum[tid] : 0;
        int x = v;
        #pragma unroll
        for (int off = 1; off < 64; off <<= 1) {
            int t = __shfl_up(x, off, 64);
            if (tid >= off) x += t;
        }
        sbo[tid] = x - v;
    }
    // stage h into X[r][128..255]
    #pragma unroll
    for (int it = 0; it < 2; ++it) {
        int s4 = tid + it * 256;
        int r = s4 >> 5, c4 = s4 & 31;
        int row = row0 + r;
        float4 v = make_float4(0, 0, 0, 0);
        if (row < n) v = *(const float4*)&h[(size_t)row * F + c4 * 4];
        *(float4*)&X[r][128 + c4 * 4] = v;
    }
    __syncthreads();   // sbo + h staged

    // ---------------- phase A: wave gathers 4 nodes serially ----------------
    const uint4* M16 = (const uint4*)Mh;   // 16B = 8 halfs; row = 16 uint4
    int sub16 = lane & 15;
    int quar  = lane >> 4;
    int2* bufw = bufa + wv * DEG_CAP;

    for (int s = 0; s < 4; ++s) {
        int lr = wv * 4 + s;
        int node = row0 + lr;
        if (node >= n) break;

        int start = rstart[node] + sbo[node >> 8];
        int end   = (node + 1 < n) ? rstart[node + 1] + sbo[(node + 1) >> 8] : e;
        int deg   = end - start;
        float qn  = q[node];

        float w[KMAX];
        int   sidx[KMAX];
        float lmax = -1e30f;

        #pragma unroll
        for (int k = 0; k < KMAX; ++k) {
            int i = start + lane + (k << 6);
            bool valid = (i < end);
            int sv = valid ? (int)src_sorted[i] : 0;
            float pv = valid ? ps_sorted[i] : 0.0f;
            float sc = pv + qn;
            float ev = (sc > 0.0f) ? sc : 0.2f * sc;
            w[k] = valid ? ev : -1e30f;
            sidx[k] = sv;
            lmax = fmaxf(lmax, w[k]);
        }
        for (int i = start + DEG_CAP + lane; i < end; i += 64) {
            float sc = ps_sorted[i] + qn;
            float ev = (sc > 0.0f) ? sc : 0.2f * sc;
            lmax = fmaxf(lmax, ev);
        }
        #pragma unroll
        for (int off = 32; off >= 1; off >>= 1)
            lmax = fmaxf(lmax, __shfl_xor(lmax, off, 64));

        float lsum = 0.0f;
        #pragma unroll
        for (int k = 0; k < KMAX; ++k) {
            float ex = (w[k] > -1e29f) ? __expf(w[k] - lmax) : 0.0f;
            w[k] = ex;
            lsum += ex;
        }
        for (int i = start + DEG_CAP + lane; i < end; i += 64) {
            float sc = ps_sorted[i] + qn;
            float ev = (sc > 0.0f) ? sc : 0.2f * sc;
            lsum += __expf(ev - lmax);
        }
        #pragma unroll
        for (int off = 32; off >= 1; off >>= 1)
            lsum += __shfl_xor(lsum, off, 64);
        float inv = 1.0f / (lsum + 1e-9f);

        #pragma unroll
        for (int k = 0; k < KMAX; ++k)
            bufw[lane + (k << 6)] = make_int2(__float_as_int(w[k] * inv), sidx[k]);

        float acc[8] = {0.f, 0.f, 0.f, 0.f, 0.f, 0.f, 0.f, 0.f};
        int lim = min(deg, DEG_CAP);
        lim = (lim + 15) & ~15;              // padded slots carry weight 0

        for (int base = 0; base < lim; base += 16) {
            int2  rr[4];
            uint4 mm[4];
            #pragma unroll
            for (int u = 0; u < 4; ++u) rr[u] = bufw[base + quar + 4 * u];
            #pragma unroll
            for (int u = 0; u < 4; ++u) mm[u] = M16[(size_t)rr[u].y * 16 + sub16];
            #pragma unroll
            for (int u = 0; u < 4; ++u) {
                float wu = __int_as_float(rr[u].x);
                const __half2* hp = (const __half2*)&mm[u];
                float2 f0 = __half22float2(hp[0]);
                float2 f1 = __half22float2(hp[1]);
                float2 f2 = __half22float2(hp[2]);
                float2 f3 = __half22float2(hp[3]);
                acc[0] = fmaf(wu, f0.x, acc[0]); acc[1] = fmaf(wu, f0.y, acc[1]);
                acc[2] = fmaf(wu, f1.x, acc[2]); acc[3] = fmaf(wu, f1.y, acc[3]);
                acc[4] = fmaf(wu, f2.x, acc[4]); acc[5] = fmaf(wu, f2.y, acc[5]);
                acc[6] = fmaf(wu, f3.x, acc[6]); acc[7] = fmaf(wu, f3.y, acc[7]);
            }
        }

        // overflow path (deg > 256): correctness-only
        for (int base = start + DEG_CAP; base < end; base += 64) {
            int i = base + lane;
            float ex = 0.f; int sv = 0;
            if (i < end) {
                sv = (int)src_sorted[i];
                float sc = ps_sorted[i] + qn;
                float ev = (sc > 0.0f) ? sc : 0.2f * sc;
                ex = __expf(ev - lmax) * inv;
            }
            bufw[lane] = make_int2(__float_as_int(ex), sv);
            for (int b2 = 0; b2 < 64; b2 += 4) {
                int2 rr = bufw[b2 + quar];
                uint4 mm = M16[(size_t)rr.y * 16 + sub16];
                float wu = __int_as_float(rr.x);
                const __half2* hp = (const __half2*)&mm;
                float2 f0 = __half22float2(hp[0]);
                float2 f1 = __half22float2(hp[1]);
                float2 f2 = __half22float2(hp[2]);
                float2 f3 = __half22float2(hp[3]);
                acc[0] = fmaf(wu, f0.x, acc[0]); acc[1] = fmaf(wu, f0.y, acc[1]);
                acc[2] = fmaf(wu, f1.x, acc[2]); acc[3] = fmaf(wu, f1.y, acc[3]);
                acc[4] = fmaf(wu, f2.x, acc[4]); acc[5] = fmaf(wu, f2.y, acc[5]);
                acc[6] = fmaf(wu, f3.x, acc[6]); acc[7] = fmaf(wu, f3.y, acc[7]);
            }
        }

        // combine the 4 quarter-waves, write agg row into X[lr][0..127]
        #pragma unroll
        for (int j = 0; j < 8; ++j) {
            acc[j] += __shfl_xor(acc[j], 16, 64);
            acc[j] += __shfl_xor(acc[j], 32, 64);
        }
        if (quar == 0) {
            *(float4*)&X[lr][sub16 * 8]     = make_float4(acc[0], acc[1], acc[2], acc[3]);
            *(float4*)&X[lr][sub16 * 8 + 4] = make_float4(acc[4], acc[5], acc[6], acc[7]);
        }
    }
    __syncthreads();   // X complete

    // ---- phase B: layer 1, K=256, wave k-slice 64 (v5 structure) ----
    int j0 = (lane & 31) * 4;
    int rh = (lane >> 5) * 8;
    float4 acc[8];
    #pragma unroll
    for (int i = 0; i < 8; ++i) acc[i] = make_float4(0.f, 0.f, 0.f, 0.f);
    int kbase = wv * 64;
    for (int k4 = 0; k4 < 16; ++k4) {
        int kk = kbase + k4 * 4;
        float4 a[8];
        #pragma unroll
        for (int r = 0; r < 8; ++r) a[r] = *(const float4*)&X[rh + r][kk];
        #pragma unroll
        for (int k = 0; k < 4; ++k) {
            float4 b = *(const float4*)&Wu[(size_t)(kk + k) * F + j0];
            #pragma unroll
            for (int r = 0; r < 8; ++r) {
                float av = k == 0 ? a[r].x : k == 1 ? a[r].y : k == 2 ? a[r].z : a[r].w;
                acc[r].x = fmaf(av, b.x, acc[r].x);
                acc[r].y = fmaf(av, b.y, acc[r].y);
                acc[r].z = fmaf(av, b.z, acc[r].z);
                acc[r].w = fmaf(av, b.w, acc[r].w);
            }
        }
    }
    __syncthreads();   // all X reads done; red aliases whole smem

    #pragma unroll
    for (int r = 0; r < 8; ++r)
        *(float4*)&smem[wv * 2048 + (rh + r) * 128 + j0] = acc[r];
    __syncthreads();

    // reduce 4 partials + bias + relu -> hn[row][col] = smem[row*128+col]
    #pragma unroll
    for (int u = 0; u < 2; ++u) {
        int idx = tid * 2 + u;
        int row = idx >> 5, c4 = (idx & 31) * 4;
        float4 s0 = *(const float4*)&smem[0 * 2048 + row * 128 + c4];
        float4 s1 = *(const float4*)&smem[1 * 2048 + row * 128 + c4];
        float4 s2 = *(const float4*)&smem[2 * 2048 + row * 128 + c4];
        float4 s3 = *(const float4*)&smem[3 * 2048 + row * 128 + c4];
        float4 bv = *(const float4*)&bu[c4];
        float4 t;
        t.x = fmaxf(s0.x + s1.x + s2.x + s3.x + bv.x, 0.f);
        t.y = fmaxf(s0.y + s1.y + s2.y + s3.y + bv.y, 0.f);
        t.z = fmaxf(s0.z + s1.z + s2.z + s3.z + bv.z, 0.f);
        t.w = fmaxf(s0.w + s1.w + s2.w + s3.w + bv.w, 0.f);
        *(float4*)&smem[row * 128 + c4] = t;   // hn (aliases red[0], owner-safe)
    }
    __syncthreads();

    // ---- layer 2: r1 = hn @ Wr1, K=128, wave k-slice 32; cols h0,h0+1 ----
    int h0 = (lane & 31) * 2;
    float r1a[8], r1b[8];
    #pragma unroll
    for (int r = 0; r < 8; ++r) { r1a[r] = 0.f; r1b[r] = 0.f; }
    int kb2 = wv * 32;
    for (int k4 = 0; k4 < 8; ++k4) {
        int kk = kb2 + k4 * 4;
        float4 a[8];
        #pragma unroll
        for (int r = 0; r < 8; ++r) a[r] = *(const float4*)&smem[(rh + r) * 128 + kk];
        #pragma unroll
        for (int k = 0; k < 4; ++k) {
            float2 b = *(const float2*)&Wr1[(size_t)(kk + k) * HID + h0];
            #pragma unroll
            for (int r = 0; r < 8; ++r) {
                float av = k == 0 ? a[r].x : k == 1 ? a[r].y : k == 2 ? a[r].z : a[r].w;
                r1a[r] = fmaf(av, b.x, r1a[r]);
                r1b[r] = fmaf(av, b.y, r1b[r]);
            }
        }
    }
    #pragma unroll
    for (int r = 0; r < 8; ++r) {
        smem[2048 + wv * 1024 + (rh + r) * 64 + h0]     = r1a[r];
        smem[2048 + wv * 1024 + (rh + r) * 64 + h0 + 1] = r1b[r];
    }
    __syncthreads();

    // ---- final: out[row] = relu(r1) @ Wr2 + br2; thread (row, 4 h's) ----
    {
        int row = tid >> 4;          // 16 rows, 16 threads each
        int hp  = (tid & 15) * 4;    // h = hp..hp+3
        float val = 0.f;
        #pragma unroll
        for (int j = 0; j < 4; ++j) {
            int hh = hp + j;
            float s = br1[hh]
                    + smem[2048 + 0 * 1024 + row * 64 + hh]
                    + smem[2048 + 1 * 1024 + row * 64 + hh]
                    + smem[2048 + 2 * 1024 + row * 64 + hh]
                    + smem[2048 + 3 * 1024 + row * 64 + hh];
            val = fmaf(fmaxf(s, 0.f), Wr2[hh], val);
        }
        #pragma unroll
        for (int off = 1; off < 16; off <<= 1) val += __shfl_xor(val, off, 64);
        int orow = row0 + row;
        if ((tid & 15) == 0 && orow < n) out[orow] = val + br2[0];
    }
}

// ---------------------------------------------------------------------------
extern "C" void kernel_launch(void* const* d_in, const int* in_sizes, int n_in,
                              void* d_out, int out_size, void* d_ws, size_t ws_size,
                              hipStream_t stream) {
    const float* h    = (const float*)d_in[0];
    const int*   src  = (const int*)d_in[1];
    const int*   dst  = (const int*)d_in[2];
    const float* W1   = (const float*)d_in[3];
    const float* b1   = (const float*)d_in[4];
    const float* W2   = (const float*)d_in[5];
    const float* b2   = (const float*)d_in[6];
    const float* nk   = (const float*)d_in[7];
    const float* attn = (const float*)d_in[8];
    const float* Wu   = (const float*)d_in[9];
    const float* bu   = (const float*)d_in[10];
    const float* Wr1  = (const float*)d_in[11];
    const float* br1  = (const float*)d_in[12];
    const float* Wr2  = (const float*)d_in[13];
    const float* br2  = (const float*)d_in[14];
    float* out = (float*)d_out;

    int n = in_sizes[0] / F;    // 10000
    int e = in_sizes[1];        // 640000
    int nb = (n + 255) / 256;   // 40
    int hb = (e + CHUNK - 1) >> CHUNK_LOG;  // 40 histogram blocks
    int mlpBlocks  = (n + NTM - 1) / NTM;   // 625
    int fusBlocks  = (n + NTU - 1) / NTU;   // 625
    int fillBlocks = (e + 255) / 256;       // 2500

    char* ws = (char*)d_ws;
    size_t off = 0;
    auto alloc = [&](size_t bytes) {
        void* pp = ws + off;
        off += (bytes + 511) & ~(size_t)511;
        return pp;
    };
    __half* Mh             = (__half*)alloc((size_t)n * F * 2);
    float* p               = (float*)alloc((size_t)n * 4);
    float* q               = (float*)alloc((size_t)n * 4);
    unsigned short* cnt    = (unsigned short*)alloc((size_t)hb * n * 2);  // -> offsets in-place
    int*   rstart          = (int*)alloc((size_t)(n + 1) * 4);
    int*   bsum            = (int*)alloc((size_t)(nb + 1) * 4);
    unsigned short* rank   = (unsigned short*)alloc((size_t)e * 2);
    unsigned short* srcsort= (unsigned short*)alloc((size_t)e * 2);
    float* pssort          = (float*)alloc((size_t)e * 4);

    fused_front<<<hb + mlpBlocks, 256, 0, stream>>>(
        dst, cnt, rank, e, n, hb,
        h, W1, b1, W2, b2, nk, attn, Mh, p, q);
    scan_block<<<nb, 1024, 0, stream>>>(cnt, rstart, bsum, n, hb);
    fill_kernel<<<fillBlocks, 256, 0, stream>>>(dst, src, rank, rstart,
                                                cnt, bsum, p, srcsort, pssort,
                                                n, nb, e);
    agg_update<<<fusBlocks, 256, 0, stream>>>(Mh, pssort, q, rstart, bsum, srcsort,
                                              h, Wu, bu, Wr1, br1, Wr2, br2,
                                              out, n, nb, e);
}

// Round 14
// 151.940 us; speedup vs baseline: 1.0452x; 1.0452x over previous
//
#include <hip/hip_runtime.h>
#include <hip/hip_bf16.h>
#include <hip/hip_fp16.h>

#define F 128
#define HID 64
#define KMAX 4
#define DEG_CAP 256   // KMAX * 64
#define NTM 16        // nodes per block in fused_front MLP
#define NTU 16        // nodes per block in agg_update
#define CHUNK_LOG 14
#define CHUNK (1 << CHUNK_LOG)   // 16384 edges per histogram block

// All sort-index arrays are u16: src ids < 10000, per-chunk rank < 16384,
// per-chunk counts <= 16384, within-bin chunk offsets <= max degree (~120).

// ---------------------------------------------------------------------------
// fused_front: blocks [0, histBlocks) build per-chunk LDS histograms (n=10000
// counters = 40KB LDS, ds_add_rtn) + per-edge local rank (u16), then dump the
// count row packed u16 to cnt[blk*n..]. No global atomics at all.
// Blocks [histBlocks, ...): node message MLP in the v5 K-split-by-wave form.
// ---------------------------------------------------------------------------
__global__ __launch_bounds__(256) void fused_front(
    const int* __restrict__ dst, unsigned short* __restrict__ cnt,
    unsigned short* __restrict__ rank,
    int e, int n, int histBlocks,
    const float* __restrict__ h,
    const float* __restrict__ W1, const float* __restrict__ b1,
    const float* __restrict__ W2, const float* __restrict__ b2,
    const float* __restrict__ nk, const float* __restrict__ attn,
    __half* __restrict__ Mh, float* __restrict__ p, float* __restrict__ q)
{
    __shared__ __align__(16) int lhist[10240];   // 40960B union
    int tid = threadIdx.x;

    if ((int)blockIdx.x < histBlocks) {
        // ---------------- LDS histogram part ----------------
        int n4 = n >> 2;
        int4* lh4 = (int4*)lhist;
        for (int i = tid; i < n4; i += 256) lh4[i] = make_int4(0, 0, 0, 0);
        for (int i = (n4 << 2) + tid; i < n; i += 256) lhist[i] = 0;
        __syncthreads();

        int base = (int)blockIdx.x << CHUNK_LOG;
        int lim = min(e - base, CHUNK);
        int lim4 = lim >> 2;
        const int4* d4 = (const int4*)(dst + base);   // base is 64KB-aligned
        for (int k = tid; k < lim4; k += 256) {
            int4 dv = d4[k];
            ushort4 rv;
            rv.x = (unsigned short)atomicAdd(&lhist[dv.x], 1);
            rv.y = (unsigned short)atomicAdd(&lhist[dv.y], 1);
            rv.z = (unsigned short)atomicAdd(&lhist[dv.z], 1);
            rv.w = (unsigned short)atomicAdd(&lhist[dv.w], 1);
            *(ushort4*)&rank[base + 4 * k] = rv;       // 8B aligned
        }
        for (int k = (lim4 << 2) + tid; k < lim; k += 256)
            rank[base + k] = (unsigned short)atomicAdd(&lhist[dst[base + k]], 1);
        __syncthreads();

        // dump counts packed 2-per-u32 (n is even)
        unsigned int* crow = (unsigned int*)(cnt + (size_t)blockIdx.x * n);
        int nh = n >> 1;
        for (int i = tid; i < nh; i += 256) {
            unsigned int v = ((unsigned int)lhist[2 * i] & 0xffffu) |
                             ((unsigned int)lhist[2 * i + 1] << 16);
            crow[i] = v;
        }
        return;
    }

    // ---------------- node MLP part (K-split by wave) ----------------
    float* smem = (float*)lhist;   // 10240 floats
    int bm = blockIdx.x - histBlocks;
    int row0 = bm * NTM;
    int wv   = tid >> 6;
    int lane = tid & 63;
    int j0 = (lane & 31) * 4;     // output col quad
    int rh = (lane >> 5) * 8;     // row-half: rows rh..rh+7

    // stage X = h[16][128] at [0,2048)
    #pragma unroll
    for (int it = 0; it < 2; ++it) {
        int s4 = tid + it * 256;
        int r = s4 >> 5, c4 = s4 & 31;
        int row = row0 + r;
        float4 v = make_float4(0, 0, 0, 0);
        if (row < n) v = *(const float4*)&h[(size_t)row * F + c4 * 4];
        *(float4*)&smem[r * F + c4 * 4] = v;
    }
    __syncthreads();

    // q = h . attn[F:]  (16 threads/row, 8 elems each)
    {
        int r = tid >> 4, kp = tid & 15;
        float qa = 0.f;
        #pragma unroll
        for (int c = 0; c < 2; ++c) {
            float4 hv = *(const float4*)&smem[r * F + kp * 8 + c * 4];
            float4 av = *(const float4*)&attn[F + kp * 8 + c * 4];
            qa = fmaf(hv.x, av.x, qa); qa = fmaf(hv.y, av.y, qa);
            qa = fmaf(hv.z, av.z, qa); qa = fmaf(hv.w, av.w, qa);
        }
        #pragma unroll
        for (int off = 1; off < 16; off <<= 1) qa += __shfl_xor(qa, off, 64);
        int row = row0 + r;
        if (kp == 0 && row < n) q[row] = qa;
    }

    // ---- layer 1: T = relu(h @ W1 + b1), K=128, wave k-slice 32 ----
    float4 acc[8];
    #pragma unroll
    for (int i = 0; i < 8; ++i) acc[i] = make_float4(0.f, 0.f, 0.f, 0.f);
    int kbase = wv * 32;
    for (int k4 = 0; k4 < 8; ++k4) {
        int kk = kbase + k4 * 4;
        float4 a[8];
        #pragma unroll
        for (int r = 0; r < 8; ++r) a[r] = *(const float4*)&smem[(rh + r) * F + kk];
        #pragma unroll
        for (int k = 0; k < 4; ++k) {
            float4 b = *(const float4*)&W1[(size_t)(kk + k) * F + j0];
            #pragma unroll
            for (int r = 0; r < 8; ++r) {
                float av = k == 0 ? a[r].x : k == 1 ? a[r].y : k == 2 ? a[r].z : a[r].w;
                acc[r].x = fmaf(av, b.x, acc[r].x);
                acc[r].y = fmaf(av, b.y, acc[r].y);
                acc[r].z = fmaf(av, b.z, acc[r].z);
                acc[r].w = fmaf(av, b.w, acc[r].w);
            }
        }
    }
    __syncthreads();   // all X reads (incl. q) done

    // red[wv][row][col] at [2048 + wv*2048)
    #pragma unroll
    for (int r = 0; r < 8; ++r)
        *(float4*)&smem[2048 + wv * 2048 + (rh + r) * 128 + j0] = acc[r];
    __syncthreads();

    // reduce + b1 + relu -> T at [0,2048)  (aliases X, dead)
    #pragma unroll
    for (int u = 0; u < 2; ++u) {
        int idx = tid * 2 + u;
        int row = idx >> 5, c4 = (idx & 31) * 4;
        float4 s0 = *(const float4*)&smem[2048 + 0 * 2048 + row * 128 + c4];
        float4 s1 = *(const float4*)&smem[2048 + 1 * 2048 + row * 128 + c4];
        float4 s2 = *(const float4*)&smem[2048 + 2 * 2048 + row * 128 + c4];
        float4 s3 = *(const float4*)&smem[2048 + 3 * 2048 + row * 128 + c4];
        float4 bv = *(const float4*)&b1[c4];
        float4 t;
        t.x = fmaxf(s0.x + s1.x + s2.x + s3.x + bv.x, 0.f);
        t.y = fmaxf(s0.y + s1.y + s2.y + s3.y + bv.y, 0.f);
        t.z = fmaxf(s0.z + s1.z + s2.z + s3.z + bv.z, 0.f);
        t.w = fmaxf(s0.w + s1.w + s2.w + s3.w + bv.w, 0.f);
        *(float4*)&smem[row * 128 + c4] = t;
    }
    __syncthreads();

    // ---- layer 2: M = T @ W2 + b2, K=128, wave k-slice 32 ----
    #pragma unroll
    for (int i = 0; i < 8; ++i) acc[i] = make_float4(0.f, 0.f, 0.f, 0.f);
    for (int k4 = 0; k4 < 8; ++k4) {
        int kk = kbase + k4 * 4;
        float4 a[8];
        #pragma unroll
        for (int r = 0; r < 8; ++r) a[r] = *(const float4*)&smem[(rh + r) * 128 + kk];
        #pragma unroll
        for (int k = 0; k < 4; ++k) {
            float4 b = *(const float4*)&W2[(size_t)(kk + k) * F + j0];
            #pragma unroll
            for (int r = 0; r < 8; ++r) {
                float av = k == 0 ? a[r].x : k == 1 ? a[r].y : k == 2 ? a[r].z : a[r].w;
                acc[r].x = fmaf(av, b.x, acc[r].x);
                acc[r].y = fmaf(av, b.y, acc[r].y);
                acc[r].z = fmaf(av, b.z, acc[r].z);
                acc[r].w = fmaf(av, b.w, acc[r].w);
            }
        }
    }
    __syncthreads();   // all T reads done
    #pragma unroll
    for (int r = 0; r < 8; ++r)
        *(float4*)&smem[2048 + wv * 2048 + (rh + r) * 128 + j0] = acc[r];
    __syncthreads();

    // reduce + b2 -> M at [0,2048)  (aliases T, dead)
    #pragma unroll
    for (int u = 0; u < 2; ++u) {
        int idx = tid * 2 + u;
        int row = idx >> 5, c4 = (idx & 31) * 4;
        float4 s0 = *(const float4*)&smem[2048 + 0 * 2048 + row * 128 + c4];
        float4 s1 = *(const float4*)&smem[2048 + 1 * 2048 + row * 128 + c4];
        float4 s2 = *(const float4*)&smem[2048 + 2 * 2048 + row * 128 + c4];
        float4 s3 = *(const float4*)&smem[2048 + 3 * 2048 + row * 128 + c4];
        float4 bv = *(const float4*)&b2[c4];
        float4 t;
        t.x = s0.x + s1.x + s2.x + s3.x + bv.x;
        t.y = s0.y + s1.y + s2.y + s3.y + bv.y;
        t.z = s0.z + s1.z + s2.z + s3.z + bv.z;
        t.w = s0.w + s1.w + s2.w + s3.w + bv.w;
        *(float4*)&smem[row * 128 + c4] = t;
    }
    __syncthreads();

    // v1 = node_kernel @ attn[:F] -> [2048,2176)  (red region, dead)
    if (tid < F) {
        float a = 0.f;
        const float4* nkr = (const float4*)&nk[(size_t)tid * F];
        const float4* at4 = (const float4*)attn;
        #pragma unroll 8
        for (int j = 0; j < 32; ++j) {
            float4 nv = nkr[j]; float4 av = at4[j];
            a = fmaf(nv.x, av.x, a); a = fmaf(nv.y, av.y, a);
            a = fmaf(nv.z, av.z, a); a = fmaf(nv.w, av.w, a);
        }
        smem[2048 + tid] = a;
    }
    __syncthreads();

    // Mh (fp16) store + p = M.v1   (thread = row, 8-col segment)
    {
        int row = tid >> 4, c8 = (tid & 15) * 8;
        int grow = row0 + row;
        float4 m0 = *(const float4*)&smem[row * 128 + c8];
        float4 m1 = *(const float4*)&smem[row * 128 + c8 + 4];
        if (grow < n) {
            __half hv[8];
            hv[0] = __float2half(m0.x); hv[1] = __float2half(m0.y);
            hv[2] = __float2half(m0.z); hv[3] = __float2half(m0.w);
            hv[4] = __float2half(m1.x); hv[5] = __float2half(m1.y);
            hv[6] = __float2half(m1.z); hv[7] = __float2half(m1.w);
            *(uint4*)&Mh[(size_t)grow * F + c8] = *(uint4*)hv;
        }
        float4 v0 = *(const float4*)&smem[2048 + c8];
        float4 v1v = *(const float4*)&smem[2048 + c8 + 4];
        float pp = m0.x * v0.x + m0.y * v0.y + m0.z * v0.z + m0.w * v0.w +
                   m1.x * v1v.x + m1.y * v1v.y + m1.z * v1v.z + m1.w * v1v.w;
        #pragma unroll
        for (int off = 1; off < 16; off <<= 1) pp += __shfl_xor(pp, off, 64);
        if ((tid & 15) == 0 && grow < n) p[grow] = pp;
    }
}

// ---------------------------------------------------------------------------
// scan_block v2: 1024 threads/block, 4 thread-groups per node each owning
// ~hb/4 chunk rows: pass-1 partial sums, LDS combine, pass-2 rewrite.
// ---------------------------------------------------------------------------
__global__ __launch_bounds__(1024) void scan_block(
    unsigned short* __restrict__ cnt, int* __restrict__ rstart,
    int* __restrict__ bsum, int n, int hb)
{
    __shared__ int psum[4][256];
    __shared__ int wsum[4];
    int tid = threadIdx.x;
    int ln = tid & 255, g = tid >> 8;          // group 0..3
    int i = blockIdx.x * 256 + ln;
    int per = (hb + 3) >> 2;
    int r0 = g * per, r1 = min(hb, r0 + per);

    // pass 1: partial sum over this group's chunk rows
    int s = 0;
    if (i < n) {
        size_t idx = (size_t)r0 * n + i;
        int r = r0;
        for (; r + 4 <= r1; r += 4) {
            int c0 = cnt[idx];
            int c1 = cnt[idx + (size_t)n];
            int c2 = cnt[idx + 2 * (size_t)n];
            int c3 = cnt[idx + 3 * (size_t)n];
            s += c0 + c1 + c2 + c3;
            idx += 4 * (size_t)n;
        }
        for (; r < r1; ++r) { s += cnt[idx]; idx += n; }
    }
    psum[g][ln] = s;
    __syncthreads();

    int base = 0;
    #pragma unroll
    for (int gg = 0; gg < 3; ++gg) base += (gg < g) ? psum[gg][ln] : 0;
    int tot = psum[0][ln] + psum[1][ln] + psum[2][ln] + psum[3][ln];

    // pass 2: rewrite this group's rows with running offsets
    if (i < n) {
        size_t idx = (size_t)r0 * n + i;
        int run = base;
        for (int r = r0; r < r1; ++r) {
            int c = cnt[idx];
            cnt[idx] = (unsigned short)run;
            run += c;
            idx += n;
        }
    }

    // rstart/bsum: group 0 scans node totals
    int lane = ln & 63, wv4 = ln >> 6;
    int x = 0, v = 0;
    if (g == 0) {
        v = (i < n) ? tot : 0;
        x = v;
        #pragma unroll
        for (int off = 1; off < 64; off <<= 1) {
            int t = __shfl_up(x, off, 64);
            if (lane >= off) x += t;
        }
        if (lane == 63) wsum[wv4] = x;
    }
    __syncthreads();
    if (g == 0) {
        int woff = 0;
        #pragma unroll
        for (int wdx = 0; wdx < 4; ++wdx) woff += (wdx < wv4) ? wsum[wdx] : 0;
        int incl = x + woff;
        if (i < n) rstart[i] = incl - v;
        if (ln == 255) bsum[blockIdx.x] = incl;
    }
}

// ---------------------------------------------------------------------------
// fill: atomic-free scatter (u16 payload); top-level bsum scan inline in LDS.
// ---------------------------------------------------------------------------
__global__ __launch_bounds__(256) void fill_kernel(
    const int* __restrict__ dst, const int* __restrict__ src,
    const unsigned short* __restrict__ rank, const int* __restrict__ rstart,
    const unsigned short* __restrict__ cntoff, const int* __restrict__ bsum,
    unsigned short* __restrict__ src_sorted, int n, int nb, int e)
{
    __shared__ int sbo[64];
    int tid = threadIdx.x;
    if (tid < 64) {
        int v = (tid < nb) ? bsum[tid] : 0;
        int x = v;
        #pragma unroll
        for (int off = 1; off < 64; off <<= 1) {
            int t = __shfl_up(x, off, 64);
            if (tid >= off) x += t;
        }
        sbo[tid] = x - v;
    }
    __syncthreads();
    int i = blockIdx.x * 256 + tid;
    if (i < e) {
        int d = dst[i];
        int rep = i >> CHUNK_LOG;
        int pos = rstart[d] + sbo[d >> 8] + (int)cntoff[(size_t)rep * n + d] + (int)rank[i];
        src_sorted[pos] = (unsigned short)src[i];
    }
}

// ---------------------------------------------------------------------------
// agg_update: FUSED segment-softmax gather + update/readout MLP.
// ---------------------------------------------------------------------------
__global__ __launch_bounds__(256) void agg_update(
    const __half* __restrict__ Mh, const float* __restrict__ p,
    const float* __restrict__ q, const int* __restrict__ rstart,
    const int* __restrict__ bsum, const unsigned short* __restrict__ src_sorted,
    const float* __restrict__ h,
    const float* __restrict__ Wu, const float* __restrict__ bu,
    const float* __restrict__ Wr1, const float* __restrict__ br1,
    const float* __restrict__ Wr2, const float* __restrict__ br2,
    float* __restrict__ out, int n, int nb, int e)
{
    __shared__ __align__(16) float smem[8192];       // 32KB union
    float (*X)[2 * F] = (float (*)[2 * F])smem;      // [16][256] = 16KB
    int2* bufa = (int2*)&smem[4096];                 // [4][DEG_CAP] = 8KB
    int*  sbo  = (int*)&smem[6144];                  // 64 ints

    int tid = threadIdx.x;
    int wv   = tid >> 6;
    int lane = tid & 63;
    int row0 = blockIdx.x * NTU;

    if (tid < 64) {
        int v = (tid < nb) ? bsum[tid] : 0;
        int x = v;
        #pragma unroll
        for (int off = 1; off < 64; off <<= 1) {
            int t = __shfl_up(x, off, 64);
            if (tid >= off) x += t;
        }
        sbo[tid] = x - v;
    }
    // stage h into X[r][128..255]
    #pragma unroll
    for (int it = 0; it < 2; ++it) {
        int s4 = tid + it * 256;
        int r = s4 >> 5, c4 = s4 & 31;
        int row = row0 + r;
        float4 v = make_float4(0, 0, 0, 0);
        if (row < n) v = *(const float4*)&h[(size_t)row * F + c4 * 4];
        *(float4*)&X[r][128 + c4 * 4] = v;
    }
    __syncthreads();   // sbo + h staged

    // ---------------- phase A: wave gathers 4 nodes serially ----------------
    const uint4* M16 = (const uint4*)Mh;   // 16B = 8 halfs; row = 16 uint4
    int sub16 = lane & 15;
    int quar  = lane >> 4;
    int2* bufw = bufa + wv * DEG_CAP;

    for (int s = 0; s < 4; ++s) {
        int lr = wv * 4 + s;
        int node = row0 + lr;
        if (node >= n) break;

        int start = rstart[node] + sbo[node >> 8];
        int end   = (node + 1 < n) ? rstart[node + 1] + sbo[(node + 1) >> 8] : e;
        int deg   = end - start;
        float qn  = q[node];

        float w[KMAX];
        int   sidx[KMAX];
        float lmax = -1e30f;

        #pragma unroll
        for (int k = 0; k < KMAX; ++k) {
            int i = start + lane + (k << 6);
            bool valid = (i < end);
            int sv = valid ? (int)src_sorted[i] : 0;
            float pv = valid ? p[sv] : 0.0f;
            float sc = pv + qn;
            float ev = (sc > 0.0f) ? sc : 0.2f * sc;
            w[k] = valid ? ev : -1e30f;
            sidx[k] = sv;
            lmax = fmaxf(lmax, w[k]);
        }
        for (int i = start + DEG_CAP + lane; i < end; i += 64) {
            float sc = p[(int)src_sorted[i]] + qn;
            float ev = (sc > 0.0f) ? sc : 0.2f * sc;
            lmax = fmaxf(lmax, ev);
        }
        #pragma unroll
        for (int off = 32; off >= 1; off >>= 1)
            lmax = fmaxf(lmax, __shfl_xor(lmax, off, 64));

        float lsum = 0.0f;
        #pragma unroll
        for (int k = 0; k < KMAX; ++k) {
            float ex = (w[k] > -1e29f) ? __expf(w[k] - lmax) : 0.0f;
            w[k] = ex;
            lsum += ex;
        }
        for (int i = start + DEG_CAP + lane; i < end; i += 64) {
            float sc = p[(int)src_sorted[i]] + qn;
            float ev = (sc > 0.0f) ? sc : 0.2f * sc;
            lsum += __expf(ev - lmax);
        }
        #pragma unroll
        for (int off = 32; off >= 1; off >>= 1)
            lsum += __shfl_xor(lsum, off, 64);
        float inv = 1.0f / (lsum + 1e-9f);

        #pragma unroll
        for (int k = 0; k < KMAX; ++k)
            bufw[lane + (k << 6)] = make_int2(__float_as_int(w[k] * inv), sidx[k]);

        float acc[8] = {0.f, 0.f, 0.f, 0.f, 0.f, 0.f, 0.f, 0.f};
        int lim = min(deg, DEG_CAP);
        lim = (lim + 15) & ~15;              // padded slots carry weight 0

        for (int base = 0; base < lim; base += 16) {
            int2  rr[4];
            uint4 mm[4];
            #pragma unroll
            for (int u = 0; u < 4; ++u) rr[u] = bufw[base + quar + 4 * u];
            #pragma unroll
            for (int u = 0; u < 4; ++u) mm[u] = M16[(size_t)rr[u].y * 16 + sub16];
            #pragma unroll
            for (int u = 0; u < 4; ++u) {
                float wu = __int_as_float(rr[u].x);
                const __half2* hp = (const __half2*)&mm[u];
                float2 f0 = __half22float2(hp[0]);
                float2 f1 = __half22float2(hp[1]);
                float2 f2 = __half22float2(hp[2]);
                float2 f3 = __half22float2(hp[3]);
                acc[0] = fmaf(wu, f0.x, acc[0]); acc[1] = fmaf(wu, f0.y, acc[1]);
                acc[2] = fmaf(wu, f1.x, acc[2]); acc[3] = fmaf(wu, f1.y, acc[3]);
                acc[4] = fmaf(wu, f2.x, acc[4]); acc[5] = fmaf(wu, f2.y, acc[5]);
                acc[6] = fmaf(wu, f3.x, acc[6]); acc[7] = fmaf(wu, f3.y, acc[7]);
            }
        }

        // overflow path (deg > 256): correctness-only
        for (int base = start + DEG_CAP; base < end; base += 64) {
            int i = base + lane;
            float ex = 0.f; int sv = 0;
            if (i < end) {
                sv = (int)src_sorted[i];
                float sc = p[sv] + qn;
                float ev = (sc > 0.0f) ? sc : 0.2f * sc;
                ex = __expf(ev - lmax) * inv;
            }
            bufw[lane] = make_int2(__float_as_int(ex), sv);
            for (int b2 = 0; b2 < 64; b2 += 4) {
                int2 rr = bufw[b2 + quar];
                uint4 mm = M16[(size_t)rr.y * 16 + sub16];
                float wu = __int_as_float(rr.x);
                const __half2* hp = (const __half2*)&mm;
                float2 f0 = __half22float2(hp[0]);
                float2 f1 = __half22float2(hp[1]);
                float2 f2 = __half22float2(hp[2]);
                float2 f3 = __half22float2(hp[3]);
                acc[0] = fmaf(wu, f0.x, acc[0]); acc[1] = fmaf(wu, f0.y, acc[1]);
                acc[2] = fmaf(wu, f1.x, acc[2]); acc[3] = fmaf(wu, f1.y, acc[3]);
                acc[4] = fmaf(wu, f2.x, acc[4]); acc[5] = fmaf(wu, f2.y, acc[5]);
                acc[6] = fmaf(wu, f3.x, acc[6]); acc[7] = fmaf(wu, f3.y, acc[7]);
            }
        }

        // combine the 4 quarter-waves, write agg row into X[lr][0..127]
        #pragma unroll
        for (int j = 0; j < 8; ++j) {
            acc[j] += __shfl_xor(acc[j], 16, 64);
            acc[j] += __shfl_xor(acc[j], 32, 64);
        }
        if (quar == 0) {
            *(float4*)&X[lr][sub16 * 8]     = make_float4(acc[0], acc[1], acc[2], acc[3]);
            *(float4*)&X[lr][sub16 * 8 + 4] = make_float4(acc[4], acc[5], acc[6], acc[7]);
        }
    }
    __syncthreads();   // X complete

    // ---- phase B: layer 1, K=256, wave k-slice 64 (v5 structure) ----
    int j0 = (lane & 31) * 4;
    int rh = (lane >> 5) * 8;
    float4 acc[8];
    #pragma unroll
    for (int i = 0; i < 8; ++i) acc[i] = make_float4(0.f, 0.f, 0.f, 0.f);
    int kbase = wv * 64;
    for (int k4 = 0; k4 < 16; ++k4) {
        int kk = kbase + k4 * 4;
        float4 a[8];
        #pragma unroll
        for (int r = 0; r < 8; ++r) a[r] = *(const float4*)&X[rh + r][kk];
        #pragma unroll
        for (int k = 0; k < 4; ++k) {
            float4 b = *(const float4*)&Wu[(size_t)(kk + k) * F + j0];
            #pragma unroll
            for (int r = 0; r < 8; ++r) {
                float av = k == 0 ? a[r].x : k == 1 ? a[r].y : k == 2 ? a[r].z : a[r].w;
                acc[r].x = fmaf(av, b.x, acc[r].x);
                acc[r].y = fmaf(av, b.y, acc[r].y);
                acc[r].z = fmaf(av, b.z, acc[r].z);
                acc[r].w = fmaf(av, b.w, acc[r].w);
            }
        }
    }
    __syncthreads();   // all X reads done; red aliases whole smem

    #pragma unroll
    for (int r = 0; r < 8; ++r)
        *(float4*)&smem[wv * 2048 + (rh + r) * 128 + j0] = acc[r];
    __syncthreads();

    // reduce 4 partials + bias + relu -> hn[row][col] = smem[row*128+col]
    #pragma unroll
    for (int u = 0; u < 2; ++u) {
        int idx = tid * 2 + u;
        int row = idx >> 5, c4 = (idx & 31) * 4;
        float4 s0 = *(const float4*)&smem[0 * 2048 + row * 128 + c4];
        float4 s1 = *(const float4*)&smem[1 * 2048 + row * 128 + c4];
        float4 s2 = *(const float4*)&smem[2 * 2048 + row * 128 + c4];
        float4 s3 = *(const float4*)&smem[3 * 2048 + row * 128 + c4];
        float4 bv = *(const float4*)&bu[c4];
        float4 t;
        t.x = fmaxf(s0.x + s1.x + s2.x + s3.x + bv.x, 0.f);
        t.y = fmaxf(s0.y + s1.y + s2.y + s3.y + bv.y, 0.f);
        t.z = fmaxf(s0.z + s1.z + s2.z + s3.z + bv.z, 0.f);
        t.w = fmaxf(s0.w + s1.w + s2.w + s3.w + bv.w, 0.f);
        *(float4*)&smem[row * 128 + c4] = t;   // hn (aliases red[0], owner-safe)
    }
    __syncthreads();

    // ---- layer 2: r1 = hn @ Wr1, K=128, wave k-slice 32; cols h0,h0+1 ----
    int h0 = (lane & 31) * 2;
    float r1a[8], r1b[8];
    #pragma unroll
    for (int r = 0; r < 8; ++r) { r1a[r] = 0.f; r1b[r] = 0.f; }
    int kb2 = wv * 32;
    for (int k4 = 0; k4 < 8; ++k4) {
        int kk = kb2 + k4 * 4;
        float4 a[8];
        #pragma unroll
        for (int r = 0; r < 8; ++r) a[r] = *(const float4*)&smem[(rh + r) * 128 + kk];
        #pragma unroll
        for (int k = 0; k < 4; ++k) {
            float2 b = *(const float2*)&Wr1[(size_t)(kk + k) * HID + h0];
            #pragma unroll
            for (int r = 0; r < 8; ++r) {
                float av = k == 0 ? a[r].x : k == 1 ? a[r].y : k == 2 ? a[r].z : a[r].w;
                r1a[r] = fmaf(av, b.x, r1a[r]);
                r1b[r] = fmaf(av, b.y, r1b[r]);
            }
        }
    }
    #pragma unroll
    for (int r = 0; r < 8; ++r) {
        smem[2048 + wv * 1024 + (rh + r) * 64 + h0]     = r1a[r];
        smem[2048 + wv * 1024 + (rh + r) * 64 + h0 + 1] = r1b[r];
    }
    __syncthreads();

    // ---- final: out[row] = relu(r1) @ Wr2 + br2; thread (row, 4 h's) ----
    {
        int row = tid >> 4;          // 16 rows, 16 threads each
        int hp  = (tid & 15) * 4;    // h = hp..hp+3
        float val = 0.f;
        #pragma unroll
        for (int j = 0; j < 4; ++j) {
            int hh = hp + j;
            float s = br1[hh]
                    + smem[2048 + 0 * 1024 + row * 64 + hh]
                    + smem[2048 + 1 * 1024 + row * 64 + hh]
                    + smem[2048 + 2 * 1024 + row * 64 + hh]
                    + smem[2048 + 3 * 1024 + row * 64 + hh];
            val = fmaf(fmaxf(s, 0.f), Wr2[hh], val);
        }
        #pragma unroll
        for (int off = 1; off < 16; off <<= 1) val += __shfl_xor(val, off, 64);
        int orow = row0 + row;
        if ((tid & 15) == 0 && orow < n) out[orow] = val + br2[0];
    }
}

// ---------------------------------------------------------------------------
extern "C" void kernel_launch(void* const* d_in, const int* in_sizes, int n_in,
                              void* d_out, int out_size, void* d_ws, size_t ws_size,
                              hipStream_t stream) {
    const float* h    = (const float*)d_in[0];
    const int*   src  = (const int*)d_in[1];
    const int*   dst  = (const int*)d_in[2];
    const float* W1   = (const float*)d_in[3];
    const float* b1   = (const float*)d_in[4];
    const float* W2   = (const float*)d_in[5];
    const float* b2   = (const float*)d_in[6];
    const float* nk   = (const float*)d_in[7];
    const float* attn = (const float*)d_in[8];
    const float* Wu   = (const float*)d_in[9];
    const float* bu   = (const float*)d_in[10];
    const float* Wr1  = (const float*)d_in[11];
    const float* br1  = (const float*)d_in[12];
    const float* Wr2  = (const float*)d_in[13];
    const float* br2  = (const float*)d_in[14];
    float* out = (float*)d_out;

    int n = in_sizes[0] / F;    // 10000
    int e = in_sizes[1];        // 640000
    int nb = (n + 255) / 256;   // 40
    int hb = (e + CHUNK - 1) >> CHUNK_LOG;  // 40 histogram blocks
    int mlpBlocks  = (n + NTM - 1) / NTM;   // 625
    int fusBlocks  = (n + NTU - 1) / NTU;   // 625
    int fillBlocks = (e + 255) / 256;       // 2500

    char* ws = (char*)d_ws;
    size_t off = 0;
    auto alloc = [&](size_t bytes) {
        void* pp = ws + off;
        off += (bytes + 511) & ~(size_t)511;
        return pp;
    };
    __half* Mh             = (__half*)alloc((size_t)n * F * 2);
    float* p               = (float*)alloc((size_t)n * 4);
    float* q               = (float*)alloc((size_t)n * 4);
    unsigned short* cnt    = (unsigned short*)alloc((size_t)hb * n * 2);  // -> offsets in-place
    int*   rstart          = (int*)alloc((size_t)(n + 1) * 4);
    int*   bsum            = (int*)alloc((size_t)(nb + 1) * 4);
    unsigned short* rank   = (unsigned short*)alloc((size_t)e * 2);
    unsigned short* srcsort= (unsigned short*)alloc((size_t)e * 2);

    fused_front<<<hb + mlpBlocks, 256, 0, stream>>>(
        dst, cnt, rank, e, n, hb,
        h, W1, b1, W2, b2, nk, attn, Mh, p, q);
    scan_block<<<nb, 1024, 0, stream>>>(cnt, rstart, bsum, n, hb);
    fill_kernel<<<fillBlocks, 256, 0, stream>>>(dst, src, rank, rstart,
                                                cnt, bsum, srcsort,
                                                n, nb, e);
    agg_update<<<fusBlocks, 256, 0, stream>>>(Mh, p, q, rstart, bsum, srcsort,
                                              h, Wu, bu, Wr1, br1, Wr2, br2,
                                              out, n, nb, e);
}